// Round 8
// baseline (315.579 us; speedup 1.0000x reference)
//
#include <hip/hip_runtime.h>
#include <math.h>

// ---------------- problem constants ----------------
constexpr int Bn  = 128;
constexpr int Kd  = 65536;    // magnitude dim (phase half of feats is zeros)
constexpr int F1  = 128;
constexpr int F2  = 64;
constexpr int NM  = 3;
constexpr int Qd  = 256;
constexpr int NCH = 512;      // split-K chunks for big GEMM (2 blocks/CU)
constexpr int KC  = 128;      // k per chunk
constexpr int MSZ = 256 * 256;

// Muon (growth) quintic Newton-Schulz coefficients
#define MA 3.4445f
#define MB (-4.7750f)
#define MC 2.0315f
// degree-9 convergent NS: x*(315 - 420y + 378y^2 - 180y^3 + 35y^4)/128, y=x^2
#define D9_0 (315.f / 128.f)
#define D9_1 (-420.f / 128.f)
#define D9_2 (378.f / 128.f)
#define D9_3 (-180.f / 128.f)
#define D9_4 (35.f / 128.f)

// ---------------- ws layout (float offsets) ----------------
constexpr size_t OFF_H1P  = 0;                                   // 512*128*128 = 8,388,608 (33.5 MB)
constexpr size_t OFF_H1   = OFF_H1P + (size_t)NCH * Bn * F1;
constexpr size_t OFF_SEL  = OFF_H1 + (size_t)Bn * F1;
constexpr size_t OFF_PART = OFF_SEL + 128;
constexpr size_t OFF_XA   = OFF_PART + 64;
constexpr size_t OFF_XB   = OFF_XA + (size_t)NM * MSZ;
constexpr size_t OFF_ACP  = OFF_XB + (size_t)NM * MSZ;           // u32: NM*128*256

// ---------------- f16 helpers ----------------
typedef __fp16 half2_t __attribute__((ext_vector_type(2)));
union HU { half2_t h; unsigned int u; };
__device__ __forceinline__ unsigned int pkh(float x, float y) {
  HU v; v.h = __builtin_amdgcn_cvt_pkrtz(x, y); return v.u;
}
__device__ __forceinline__ half2_t uh(unsigned int u) { HU v; v.u = u; return v.h; }

#if __has_builtin(__builtin_amdgcn_fdot2)
#define FDOT2(a, b, c) __builtin_amdgcn_fdot2((a), (b), (c), false)
#else
#define FDOT2(a, b, c) ((c) + (float)(a)[0] * (float)(b)[0] + (float)(a)[1] * (float)(b)[1])
#endif

// ---------------- K1: split-K magnitude GEMM (LDS double-buffered) ----------------
// 512 blocks x 512 thr; block = k-chunk of 128; 4 subtiles of 32 k; 2 blocks/CU.
__global__ __launch_bounds__(512) void k_gemm1(const float* __restrict__ sp,
                                               const float* __restrict__ W1,
                                               float* __restrict__ h1p) {
  __shared__ union SM {
    float stage[2][2][32][132];   // [buf][A/W][k][rowcol]
    float comb[256][65];
  } sm;
  const int t  = threadIdx.x;
  const int ch = blockIdx.x;
  const size_t k0 = (size_t)ch * KC;
  const int u = t & 255;
  const int h = t >> 8;            // k-half within subtile
  const int r0 = (u >> 4) * 4;     // rows {r0, r0+64}
  const int c0 = (u & 15) * 4;     // cols {c0, c0+64}
  const int srow = t >> 3;
  const int squad = t & 7;

  float acc[2][2][4][4];
#pragma unroll
  for (int ri = 0; ri < 2; ++ri)
#pragma unroll
    for (int ci = 0; ci < 2; ++ci)
#pragma unroll
      for (int i = 0; i < 4; ++i)
#pragma unroll
        for (int j = 0; j < 4; ++j) acc[ri][ci][i][j] = 0.f;

  float4 ra0, ra1, rw0, rw1;
  {
    const size_t kb = k0 + squad * 4;
    ra0 = *(const float4*)(sp + (size_t)srow * Kd + kb);
    ra1 = *(const float4*)(sp + (size_t)(srow + 64) * Kd + kb);
    rw0 = *(const float4*)(W1 + (size_t)srow * (2 * Kd) + kb);
    rw1 = *(const float4*)(W1 + (size_t)(srow + 64) * (2 * Kd) + kb);
  }
#pragma unroll
  for (int e = 0; e < 4; ++e) {
    sm.stage[0][0][squad * 4 + e][srow]      = fabsf((&ra0.x)[e]);
    sm.stage[0][0][squad * 4 + e][srow + 64] = fabsf((&ra1.x)[e]);
    sm.stage[0][1][squad * 4 + e][srow]      = (&rw0.x)[e];
    sm.stage[0][1][squad * 4 + e][srow + 64] = (&rw1.x)[e];
  }
  __syncthreads();

#pragma unroll
  for (int kt = 0; kt < 4; ++kt) {
    const int cur = kt & 1;
    if (kt < 3) {   // issue next-subtile loads; land during compute
      const size_t kb = k0 + (kt + 1) * 32 + squad * 4;
      ra0 = *(const float4*)(sp + (size_t)srow * Kd + kb);
      ra1 = *(const float4*)(sp + (size_t)(srow + 64) * Kd + kb);
      rw0 = *(const float4*)(W1 + (size_t)srow * (2 * Kd) + kb);
      rw1 = *(const float4*)(W1 + (size_t)(srow + 64) * (2 * Kd) + kb);
    }
    const float (*As)[132] = sm.stage[cur][0];
    const float (*Ws)[132] = sm.stage[cur][1];
#pragma unroll
    for (int qq = 0; qq < 16; ++qq) {
      const int q = h * 16 + qq;
      const float4 a0 = *(const float4*)&As[q][r0];
      const float4 a1 = *(const float4*)&As[q][r0 + 64];
      const float4 w0 = *(const float4*)&Ws[q][c0];
      const float4 w1 = *(const float4*)&Ws[q][c0 + 64];
      const float av[2][4] = {{a0.x, a0.y, a0.z, a0.w}, {a1.x, a1.y, a1.z, a1.w}};
      const float wv[2][4] = {{w0.x, w0.y, w0.z, w0.w}, {w1.x, w1.y, w1.z, w1.w}};
#pragma unroll
      for (int ri = 0; ri < 2; ++ri)
#pragma unroll
        for (int ci = 0; ci < 2; ++ci)
#pragma unroll
          for (int i = 0; i < 4; ++i)
#pragma unroll
            for (int j = 0; j < 4; ++j)
              acc[ri][ci][i][j] += av[ri][i] * wv[ci][j];
    }
    if (kt < 3) {
      const int nxt = cur ^ 1;
#pragma unroll
      for (int e = 0; e < 4; ++e) {
        sm.stage[nxt][0][squad * 4 + e][srow]      = fabsf((&ra0.x)[e]);
        sm.stage[nxt][0][squad * 4 + e][srow + 64] = fabsf((&ra1.x)[e]);
        sm.stage[nxt][1][squad * 4 + e][srow]      = (&rw0.x)[e];
        sm.stage[nxt][1][squad * 4 + e][srow + 64] = (&rw1.x)[e];
      }
    }
    __syncthreads();
  }

  // combine k-halves through comb
  float* af = &acc[0][0][0][0];
  if (h == 1) {
#pragma unroll
    for (int p = 0; p < 64; ++p) sm.comb[u][p] = af[p];
  }
  __syncthreads();
  if (h == 0) {
#pragma unroll
    for (int p = 0; p < 64; ++p) af[p] += sm.comb[u][p];
    float* outp = h1p + (size_t)ch * (Bn * F1);
#pragma unroll
    for (int ri = 0; ri < 2; ++ri)
#pragma unroll
      for (int i = 0; i < 4; ++i) {
        const int row = r0 + ri * 64 + i;
#pragma unroll
        for (int ci = 0; ci < 2; ++ci)
          *(float4*)&outp[row * F1 + c0 + ci * 64] =
              make_float4(acc[ri][ci][i][0], acc[ri][ci][i][1],
                          acc[ri][ci][i][2], acc[ri][ci][i][3]);
      }
  }
}

// ---------------- K1b: reduce partials + bias + relu (512 chunks) ----------------
__global__ __launch_bounds__(256) void k_red(const float* __restrict__ h1p,
                                             const float* __restrict__ b1,
                                             float* __restrict__ h1) {
  const int t = threadIdx.x;
  const int ol = t & 63;
  const int g = t >> 6;
  const int o = blockIdx.x * 64 + ol;
  double s = 0.0;
#pragma unroll 8
  for (int c = g * 128; c < g * 128 + 128; ++c)
    s += (double)h1p[(size_t)c * (Bn * F1) + o];
  __shared__ double red[4][64];
  red[g][ol] = s;
  __syncthreads();
  if (g == 0) {
    const double v = red[0][ol] + red[1][ol] + red[2][ol] + red[3][ol];
    const float r = (float)v + b1[o & 127];
    h1[o] = fmaxf(r, 0.f);
  }
}

// ---------------- K2: small MLP + syndrome + selection ----------------
__global__ __launch_bounds__(256) void k_mlp(const float* __restrict__ h1,
                                             const float* __restrict__ W2,
                                             const float* __restrict__ b2,
                                             const float* __restrict__ W3,
                                             const float* __restrict__ b3,
                                             int* __restrict__ sel) {
  const int t = threadIdx.x;
  const int b0 = blockIdx.x * 16;
  __shared__ float h2s[16 * 64];
  for (int o = t; o < 16 * 64; o += 256) {
    const int bl = o >> 6, j = o & 63;
    const float* hr = h1 + (b0 + bl) * F1;
    const float* wr = W2 + j * F1;
    float s = b2[j];
    for (int k = 0; k < F1; ++k) s += hr[k] * wr[k];
    h2s[o] = fmaxf(s, 0.f);
  }
  __syncthreads();
  if (t < 16) {
    const int b = b0 + t;
    float best = -1.f;
    int bi = 0;
    bool needed = false;
    for (int j = 0; j < 8; ++j) {
      double s = (double)b3[j];
      const float* wr = W3 + j * F2;
      for (int k = 0; k < F2; ++k) s += (double)h2s[t * F2 + k] * (double)wr[k];
      const float a = fabsf((float)s);
      if (a > 1e-4f) needed = true;
      if (a > best) { best = a; bi = j; }
    }
    sel[b] = needed ? (bi % NM) : -1;
  }
}

// ---------------- NS phase A: A = X^T X -> f16 colpk (symmetric 32x32 tiles) ----------------
__global__ __launch_bounds__(512) void k_pA(const float* __restrict__ Xs,
                                            unsigned int* __restrict__ Acp,
                                            float* __restrict__ part) {
  const int bid = blockIdx.x;
  const int m = bid / 36;
  int rem = bid % 36;
  int I = 0;
  while (rem >= 8 - I) { rem -= 8 - I; ++I; }
  const int J = I + rem;
  const float* Xm = Xs + (size_t)m * MSZ;
  unsigned int* Am = Acp + (size_t)m * (128 * 256);
  __shared__ float PI[32][260];
  __shared__ float PJb[32][260];
  __shared__ float red[7][64][17];
  __shared__ float tr8[8];
  float (*PJ)[260] = (I == J) ? PI : PJb;
  const int t = threadIdx.x;

#pragma unroll
  for (int it = 0; it < 4; ++it) {
    const int task = it * 512 + t;
    const int k = task >> 3, c4 = task & 7;
    const float4 vI = *(const float4*)&Xm[k * 256 + I * 32 + c4 * 4];
#pragma unroll
    for (int e = 0; e < 4; ++e) PI[c4 * 4 + e][k] = (&vI.x)[e];
    if (I != J) {
      const float4 vJ = *(const float4*)&Xm[k * 256 + J * 32 + c4 * 4];
#pragma unroll
      for (int e = 0; e < 4; ++e) PJb[c4 * 4 + e][k] = (&vJ.x)[e];
    }
  }
  __syncthreads();

  const int h = t >> 6, u = t & 63, ur = u >> 3, uc = u & 7;
  float a[4][4];
#pragma unroll
  for (int i = 0; i < 4; ++i)
#pragma unroll
    for (int j = 0; j < 4; ++j) a[i][j] = 0.f;

  const int kb = h * 32;
#pragma unroll 8
  for (int kk = 0; kk < 32; ++kk) {
    const int k = kb + kk;
    float xi[4], xj[4];
#pragma unroll
    for (int i = 0; i < 4; ++i) xi[i] = PI[ur * 4 + i][k];
#pragma unroll
    for (int j = 0; j < 4; ++j) xj[j] = PJ[uc * 4 + j][k];
#pragma unroll
    for (int i = 0; i < 4; ++i)
#pragma unroll
      for (int j = 0; j < 4; ++j) a[i][j] += xi[i] * xj[j];
  }
  if (h) {
    float* rr = &red[h - 1][u][0];
#pragma unroll
    for (int i = 0; i < 4; ++i)
#pragma unroll
      for (int j = 0; j < 4; ++j) rr[i * 4 + j] = a[i][j];
  }
  __syncthreads();
  if (h == 0) {
#pragma unroll
    for (int i = 0; i < 4; ++i)
#pragma unroll
      for (int j = 0; j < 4; ++j) {
        float s = a[i][j];
#pragma unroll
        for (int q = 0; q < 7; ++q) s += red[q][u][i * 4 + j];
        a[i][j] = s;
      }
    const int gr = I * 32 + ur * 4, gc = J * 32 + uc * 4;
    {
      const int kp = gr >> 1;
      *(uint4*)&Am[kp * 256 + gc] =
          make_uint4(pkh(a[0][0], a[1][0]), pkh(a[0][1], a[1][1]),
                     pkh(a[0][2], a[1][2]), pkh(a[0][3], a[1][3]));
      *(uint4*)&Am[(kp + 1) * 256 + gc] =
          make_uint4(pkh(a[2][0], a[3][0]), pkh(a[2][1], a[3][1]),
                     pkh(a[2][2], a[3][2]), pkh(a[2][3], a[3][3]));
    }
    if (I != J) {
      const int kp = gc >> 1;
      *(uint4*)&Am[kp * 256 + gr] =
          make_uint4(pkh(a[0][0], a[0][1]), pkh(a[1][0], a[1][1]),
                     pkh(a[2][0], a[2][1]), pkh(a[3][0], a[3][1]));
      *(uint4*)&Am[(kp + 1) * 256 + gr] =
          make_uint4(pkh(a[0][2], a[0][3]), pkh(a[1][2], a[1][3]),
                     pkh(a[2][2], a[2][3]), pkh(a[3][2], a[3][3]));
    } else if (ur == uc) {
      tr8[ur] = a[0][0] + a[1][1] + a[2][2] + a[3][3];
    }
  }
  if (I == J) {
    __syncthreads();
    if (t == 0) {
      float s = 0.f;
#pragma unroll
      for (int q = 0; q < 8; ++q) s += tr8[q];
      part[m * 8 + I] = s;
    }
  }
}

// ---------------- NS phase B: X' = sum_p c[p]*X*A^p, npass chained passes ----------------
// A register-cached (16 uint4 per thread, shared across all passes).
__global__ __launch_bounds__(512) void k_pB(const float* __restrict__ Xs,
                                            const unsigned int* __restrict__ Acp,
                                            const float* __restrict__ part,
                                            float* __restrict__ Xn,
                                            const float q0, const float q1, const float q2,
                                            const float q3, const float q4,
                                            const int npass, const int first) {
  const int m = blockIdx.x >> 6, g = blockIdx.x & 63, i0 = g * 4;
  const float* Xm = Xs + (size_t)m * MSZ;
  const uint4* A4 = (const uint4*)(Acp + (size_t)m * (128 * 256));
  float* Xo = Xn + (size_t)m * MSZ;
  const int t = threadIdx.x, h = t >> 6, u = t & 63;
  __shared__ float xs[4][260];
  __shared__ unsigned int buf0[4][132];
  __shared__ unsigned int buf1[4][132];
  __shared__ float red[7][64][17];

  float c[5] = {q0, q1, q2, q3, q4};
  if (first) {
    float tr = 0.f;
#pragma unroll
    for (int q = 0; q < 8; ++q) tr += part[m * 8 + q];
    const float s = 0.15f * sqrtf(tr);     // 1.2 * 2*||C||_F/sqrt(256)
    const float is = 1.f / s, is2 = is * is;
    c[0] *= is;
    c[1] *= is * is2;
    c[2] *= is * is2 * is2;
  }

  if (t < 256) {  // stage X strip: fp32 + f16 pairs along k
    const int r = t >> 6, c16 = t & 63;
    const float4 v = *(const float4*)&Xm[(i0 + r) * 256 + c16 * 4];
    *(float4*)&xs[r][c16 * 4] = v;
    buf0[r][2 * c16]     = pkh(v.x, v.y);
    buf0[r][2 * c16 + 1] = pkh(v.z, v.w);
  }

  // prefetch all 16 A-rows for this thread's kp range (reused by every pass)
  const int kp0 = h * 16;
  uint4 areg[16];
#pragma unroll
  for (int kk = 0; kk < 16; ++kk) areg[kk] = A4[(kp0 + kk) * 64 + u];

  __syncthreads();

  float out[4][4];
  if (h == 0) {
#pragma unroll
    for (int i = 0; i < 4; ++i)
#pragma unroll
      for (int j = 0; j < 4; ++j) out[i][j] = c[0] * xs[i][u * 4 + j];
  }

  unsigned int (*src)[132] = buf0;
  unsigned int (*dst)[132] = buf1;
  for (int p = 1; p <= npass; ++p) {
    float acc[4][4];
#pragma unroll
    for (int i = 0; i < 4; ++i)
#pragma unroll
      for (int j = 0; j < 4; ++j) acc[i][j] = 0.f;
#pragma unroll 8
    for (int kk = 0; kk < 16; ++kk) {
      const int kp = kp0 + kk;
      const uint4 aw = areg[kk];
      const half2_t b0 = uh(aw.x), b1 = uh(aw.y), b2 = uh(aw.z), b3 = uh(aw.w);
#pragma unroll
      for (int r = 0; r < 4; ++r) {
        const half2_t xp = uh(src[r][kp]);
        acc[r][0] = FDOT2(xp, b0, acc[r][0]);
        acc[r][1] = FDOT2(xp, b1, acc[r][1]);
        acc[r][2] = FDOT2(xp, b2, acc[r][2]);
        acc[r][3] = FDOT2(xp, b3, acc[r][3]);
      }
    }
    if (h) {
      float* rr = &red[h - 1][u][0];
#pragma unroll
      for (int i = 0; i < 4; ++i)
#pragma unroll
        for (int j = 0; j < 4; ++j) rr[i * 4 + j] = acc[i][j];
    }
    __syncthreads();
    if (h == 0) {
      float tv[4][4];
#pragma unroll
      for (int i = 0; i < 4; ++i)
#pragma unroll
        for (int j = 0; j < 4; ++j) {
          float s = acc[i][j];
#pragma unroll
          for (int q = 0; q < 7; ++q) s += red[q][u][i * 4 + j];
          tv[i][j] = s;
          out[i][j] += c[p] * s;
        }
      if (p < npass) {
#pragma unroll
        for (int i = 0; i < 4; ++i) {
          dst[i][2 * u]     = pkh(tv[i][0], tv[i][1]);
          dst[i][2 * u + 1] = pkh(tv[i][2], tv[i][3]);
        }
      }
    }
    __syncthreads();  // red reads done; dst ready for next pass
    unsigned int (*tmp)[132] = src; src = dst; dst = tmp;
  }

  if (h == 0) {
#pragma unroll
    for (int i = 0; i < 4; ++i)
      *(float4*)&Xo[(i0 + i) * 256 + u * 4] =
          make_float4(out[i][0], out[i][1], out[i][2], out[i][3]);
  }
}

// ---------------- K4: output assembly ----------------
__global__ __launch_bounds__(256) void k_out(const float* __restrict__ sp,
                                             const float* __restrict__ P,
                                             const int* __restrict__ sel,
                                             float* __restrict__ out) {
  const int t = threadIdx.x;
  if (blockIdx.x < 128) {
    const int b = blockIdx.x;
    __shared__ float hd[256];
    hd[t] = sp[(size_t)b * Kd + t];
    __syncthreads();
    const int s = sel[b];
    if (s < 0) {
      out[(size_t)b * Kd + t] = hd[t];
    } else {
      const float4* prow = (const float4*)(P + (size_t)s * MSZ + t * 256);
      float acc = 0.f;
#pragma unroll 8
      for (int j4 = 0; j4 < 64; ++j4) {
        const float4 p = prow[j4];
        acc += p.x * hd[4 * j4 + 0] + p.y * hd[4 * j4 + 1] +
               p.z * hd[4 * j4 + 2] + p.w * hd[4 * j4 + 3];
      }
      out[(size_t)b * Kd + t] = hd[t] + 0.1f * acc;
    }
  } else {
    const int ci = blockIdx.x - 128;
    const float4* in4 = (const float4*)sp;
    float4* out4 = (float4*)out;
    const int total = Bn * (Kd / 4);
    for (int i = ci * 256 + t; i < total; i += 2048 * 256) {
      const int pos = i & ((Kd / 4) - 1);
      if (pos >= Qd / 4) out4[i] = in4[i];
    }
  }
}

// ---------------- host ----------------
extern "C" void kernel_launch(void* const* d_in, const int* in_sizes, int n_in,
                              void* d_out, int out_size, void* d_ws, size_t ws_size,
                              hipStream_t stream) {
  (void)in_sizes; (void)n_in; (void)out_size; (void)ws_size;
  const float* sp = (const float*)d_in[0];
  const float* W1 = (const float*)d_in[1];
  const float* b1 = (const float*)d_in[2];
  const float* W2 = (const float*)d_in[3];
  const float* b2 = (const float*)d_in[4];
  const float* W3 = (const float*)d_in[5];
  const float* b3 = (const float*)d_in[6];
  const float* ops = (const float*)d_in[7];
  float* out = (float*)d_out;
  float* ws = (float*)d_ws;

  float* h1p  = ws + OFF_H1P;
  float* h1   = ws + OFF_H1;
  int*   sel  = (int*)(ws + OFF_SEL);
  float* part = ws + OFF_PART;
  float* Xa   = ws + OFF_XA;
  float* Xb   = ws + OFF_XB;
  unsigned int* Acp = (unsigned int*)(ws + OFF_ACP);

  k_gemm1<<<NCH, 512, 0, stream>>>(sp, W1, h1p);
  k_red<<<256, 256, 0, stream>>>(h1p, b1, h1);
  k_mlp<<<8, 256, 0, stream>>>(h1, W2, b2, W3, b3, sel);

  // iteration 0 on raw C (scale folded via trace partials)
  k_pA<<<NM * 36, 512, 0, stream>>>(ops, Acp, part);
  k_pB<<<192, 512, 0, stream>>>(ops, Acp, part, Xa, MA, MB, MC, 0.f, 0.f, 2, 1);

  float* X = Xa;
  float* Xn = Xb;
  for (int it = 1; it < 9; ++it) {  // its 1..7 Muon, it 8 = degree-9 convergent
    k_pA<<<NM * 36, 512, 0, stream>>>(X, Acp, part);
    if (it < 8) {
      k_pB<<<192, 512, 0, stream>>>(X, Acp, part, Xn, MA, MB, MC, 0.f, 0.f, 2, 0);
    } else {
      k_pB<<<192, 512, 0, stream>>>(X, Acp, part, Xn, D9_0, D9_1, D9_2, D9_3, D9_4, 4, 0);
    }
    float* tmp = X; X = Xn; Xn = tmp;
  }

  k_out<<<128 + 2048, 256, 0, stream>>>(sp, X, sel, out);
}

// Round 9
// 219.165 us; speedup vs baseline: 1.4399x; 1.4399x over previous
//
#include <hip/hip_runtime.h>
#include <math.h>

// ---------------- problem constants ----------------
constexpr int Bn  = 128;
constexpr int Kd  = 65536;    // magnitude dim (phase half of feats is zeros)
constexpr int F1  = 128;
constexpr int F2  = 64;
constexpr int NM  = 3;
constexpr int Qd  = 256;
constexpr int NCH = 512;      // split-K chunks for big GEMM
constexpr int KC  = 128;      // k per chunk
constexpr int MSZ = 256 * 256;

// Muon (growth) quintic Newton-Schulz coefficients
#define MA 3.4445f
#define MB (-4.7750f)
#define MC 2.0315f
// degree-9 convergent NS: x*(315 - 420y + 378y^2 - 180y^3 + 35y^4)/128, y=x^2
#define D9_0 (315.f / 128.f)
#define D9_1 (-420.f / 128.f)
#define D9_2 (378.f / 128.f)
#define D9_3 (-180.f / 128.f)
#define D9_4 (35.f / 128.f)

// ---------------- ws layout (float offsets) ----------------
constexpr size_t OFF_H1P  = 0;                                   // 512*128*128 floats
constexpr size_t OFF_H1   = OFF_H1P + (size_t)NCH * Bn * F1;
constexpr size_t OFF_SEL  = OFF_H1 + (size_t)Bn * F1;
constexpr size_t OFF_PART = OFF_SEL + 128;
constexpr size_t OFF_XA   = OFF_PART + 64;
constexpr size_t OFF_XB   = OFF_XA + (size_t)NM * MSZ;
constexpr size_t OFF_ACP  = OFF_XB + (size_t)NM * MSZ;           // u32: NM*128*256

// ---------------- f16 helpers ----------------
typedef __fp16 half2_t __attribute__((ext_vector_type(2)));
union HU { half2_t h; unsigned int u; };
__device__ __forceinline__ unsigned int pkh(float x, float y) {
  HU v; v.h = __builtin_amdgcn_cvt_pkrtz(x, y); return v.u;
}
__device__ __forceinline__ half2_t uh(unsigned int u) { HU v; v.u = u; return v.h; }

#if __has_builtin(__builtin_amdgcn_fdot2)
#define FDOT2(a, b, c) __builtin_amdgcn_fdot2((a), (b), (c), false)
#else
#define FDOT2(a, b, c) ((c) + (float)(a)[0] * (float)(b)[0] + (float)(a)[1] * (float)(b)[1])
#endif

// ---------------- K1: split-K magnitude GEMM ----------------
// 512 blocks x 512 thr; block = k-chunk of 128; 4 subtiles of 32 k.
// Single 33.8 KB LDS buffer (2 blocks/CU) + register prefetch of next subtile.
__global__ __launch_bounds__(512) void k_gemm1(const float* __restrict__ sp,
                                               const float* __restrict__ W1,
                                               float* __restrict__ h1p) {
  __shared__ float smem[2][32][132];   // [0]=As, [1]=Ws; aliased as combine buf
  float (*As)[132] = smem[0];
  float (*Ws)[132] = smem[1];
  const int t  = threadIdx.x;
  const int ch = blockIdx.x;
  const size_t k0 = (size_t)ch * KC;
  const int u = t & 255;
  const int h = t >> 8;            // k-half: q = h*16 + qq within each subtile
  const int r0 = (u >> 4) * 4;     // rows {r0, r0+64}
  const int c0 = (u & 15) * 4;     // cols {c0, c0+64}
  const int srow = t >> 3;         // staging rows srow, srow+64
  const int squad = t & 7;         // staging k-quad

  float acc[2][2][4][4];
#pragma unroll
  for (int ri = 0; ri < 2; ++ri)
#pragma unroll
    for (int ci = 0; ci < 2; ++ci)
#pragma unroll
      for (int i = 0; i < 4; ++i)
#pragma unroll
        for (int j = 0; j < 4; ++j) acc[ri][ci][i][j] = 0.f;

  float4 ra0, ra1, rw0, rw1;
  {
    const size_t kb = k0 + squad * 4;
    ra0 = *(const float4*)(sp + (size_t)srow * Kd + kb);
    ra1 = *(const float4*)(sp + (size_t)(srow + 64) * Kd + kb);
    rw0 = *(const float4*)(W1 + (size_t)srow * (2 * Kd) + kb);
    rw1 = *(const float4*)(W1 + (size_t)(srow + 64) * (2 * Kd) + kb);
  }

#pragma unroll
  for (int kt = 0; kt < 4; ++kt) {
    __syncthreads();
#pragma unroll
    for (int e = 0; e < 4; ++e) {
      As[squad * 4 + e][srow]      = fabsf((&ra0.x)[e]);
      As[squad * 4 + e][srow + 64] = fabsf((&ra1.x)[e]);
      Ws[squad * 4 + e][srow]      = (&rw0.x)[e];
      Ws[squad * 4 + e][srow + 64] = (&rw1.x)[e];
    }
    __syncthreads();
    if (kt < 3) {  // prefetch next subtile; lands during compute below
      const size_t kb = k0 + (kt + 1) * 32 + squad * 4;
      ra0 = *(const float4*)(sp + (size_t)srow * Kd + kb);
      ra1 = *(const float4*)(sp + (size_t)(srow + 64) * Kd + kb);
      rw0 = *(const float4*)(W1 + (size_t)srow * (2 * Kd) + kb);
      rw1 = *(const float4*)(W1 + (size_t)(srow + 64) * (2 * Kd) + kb);
    }
#pragma unroll
    for (int qq = 0; qq < 16; ++qq) {
      const int q = h * 16 + qq;
      const float4 a0 = *(const float4*)&As[q][r0];
      const float4 a1 = *(const float4*)&As[q][r0 + 64];
      const float4 w0 = *(const float4*)&Ws[q][c0];
      const float4 w1 = *(const float4*)&Ws[q][c0 + 64];
      const float av[2][4] = {{a0.x, a0.y, a0.z, a0.w}, {a1.x, a1.y, a1.z, a1.w}};
      const float wv[2][4] = {{w0.x, w0.y, w0.z, w0.w}, {w1.x, w1.y, w1.z, w1.w}};
#pragma unroll
      for (int ri = 0; ri < 2; ++ri)
#pragma unroll
        for (int ci = 0; ci < 2; ++ci)
#pragma unroll
          for (int i = 0; i < 4; ++i)
#pragma unroll
            for (int j = 0; j < 4; ++j)
              acc[ri][ci][i][j] += av[ri][i] * wv[ci][j];
    }
  }

  // combine the two k-halves through LDS (2 rounds of 128 slots, stride 66)
  float* comb = (float*)smem;
  float* af = &acc[0][0][0][0];
#pragma unroll
  for (int r = 0; r < 2; ++r) {
    __syncthreads();
    if (h == 1 && ((u >> 7) == r)) {
      const int slot = u & 127;
#pragma unroll
      for (int p = 0; p < 32; ++p)
        *(float2*)&comb[slot * 66 + p * 2] = make_float2(af[p * 2], af[p * 2 + 1]);
    }
    __syncthreads();
    if (h == 0 && ((u >> 7) == r)) {
      const int slot = u & 127;
#pragma unroll
      for (int p = 0; p < 64; ++p) af[p] += comb[slot * 66 + p];
    }
  }

  if (h == 0) {
    float* outp = h1p + (size_t)ch * (Bn * F1);
#pragma unroll
    for (int ri = 0; ri < 2; ++ri)
#pragma unroll
      for (int i = 0; i < 4; ++i) {
        const int row = r0 + ri * 64 + i;
#pragma unroll
        for (int ci = 0; ci < 2; ++ci)
          *(float4*)&outp[row * F1 + c0 + ci * 64] =
              make_float4(acc[ri][ci][i][0], acc[ri][ci][i][1],
                          acc[ri][ci][i][2], acc[ri][ci][i][3]);
      }
  }
}

// ---------------- K1b: reduce partials + bias + relu (512 chunks) ----------------
__global__ __launch_bounds__(256) void k_red(const float* __restrict__ h1p,
                                             const float* __restrict__ b1,
                                             float* __restrict__ h1) {
  const int t = threadIdx.x;
  const int ol = t & 63;
  const int g = t >> 6;
  const int o = blockIdx.x * 64 + ol;
  double s = 0.0;
#pragma unroll 8
  for (int c = g * 128; c < g * 128 + 128; ++c)
    s += (double)h1p[(size_t)c * (Bn * F1) + o];
  __shared__ double red[4][64];
  red[g][ol] = s;
  __syncthreads();
  if (g == 0) {
    const double v = red[0][ol] + red[1][ol] + red[2][ol] + red[3][ol];
    const float r = (float)v + b1[o & 127];
    h1[o] = fmaxf(r, 0.f);
  }
}

// ---------------- K2: small MLP + syndrome + selection ----------------
__global__ __launch_bounds__(256) void k_mlp(const float* __restrict__ h1,
                                             const float* __restrict__ W2,
                                             const float* __restrict__ b2,
                                             const float* __restrict__ W3,
                                             const float* __restrict__ b3,
                                             int* __restrict__ sel) {
  const int t = threadIdx.x;
  const int b0 = blockIdx.x * 16;
  __shared__ float h2s[16 * 64];
  for (int o = t; o < 16 * 64; o += 256) {
    const int bl = o >> 6, j = o & 63;
    const float* hr = h1 + (b0 + bl) * F1;
    const float* wr = W2 + j * F1;
    float s = b2[j];
    for (int k = 0; k < F1; ++k) s += hr[k] * wr[k];
    h2s[o] = fmaxf(s, 0.f);
  }
  __syncthreads();
  if (t < 16) {
    const int b = b0 + t;
    float best = -1.f;
    int bi = 0;
    bool needed = false;
    for (int j = 0; j < 8; ++j) {
      double s = (double)b3[j];
      const float* wr = W3 + j * F2;
      for (int k = 0; k < F2; ++k) s += (double)h2s[t * F2 + k] * (double)wr[k];
      const float a = fabsf((float)s);
      if (a > 1e-4f) needed = true;
      if (a > best) { best = a; bi = j; }
    }
    sel[b] = needed ? (bi % NM) : -1;
  }
}

// ---------------- NS phase A: A = X^T X -> f16 colpk (symmetric 32x32 tiles) ----------------
__global__ __launch_bounds__(512) void k_pA(const float* __restrict__ Xs,
                                            unsigned int* __restrict__ Acp,
                                            float* __restrict__ part) {
  const int bid = blockIdx.x;
  const int m = bid / 36;
  int rem = bid % 36;
  int I = 0;
  while (rem >= 8 - I) { rem -= 8 - I; ++I; }
  const int J = I + rem;
  const float* Xm = Xs + (size_t)m * MSZ;
  unsigned int* Am = Acp + (size_t)m * (128 * 256);
  __shared__ float PI[32][260];
  __shared__ float PJb[32][260];
  __shared__ float red[7][64][17];
  __shared__ float tr8[8];
  float (*PJ)[260] = (I == J) ? PI : PJb;
  const int t = threadIdx.x;

#pragma unroll
  for (int it = 0; it < 4; ++it) {
    const int task = it * 512 + t;
    const int k = task >> 3, c4 = task & 7;
    const float4 vI = *(const float4*)&Xm[k * 256 + I * 32 + c4 * 4];
#pragma unroll
    for (int e = 0; e < 4; ++e) PI[c4 * 4 + e][k] = (&vI.x)[e];
    if (I != J) {
      const float4 vJ = *(const float4*)&Xm[k * 256 + J * 32 + c4 * 4];
#pragma unroll
      for (int e = 0; e < 4; ++e) PJb[c4 * 4 + e][k] = (&vJ.x)[e];
    }
  }
  __syncthreads();

  const int h = t >> 6, u = t & 63, ur = u >> 3, uc = u & 7;
  float a[4][4];
#pragma unroll
  for (int i = 0; i < 4; ++i)
#pragma unroll
    for (int j = 0; j < 4; ++j) a[i][j] = 0.f;

  const int kb = h * 32;
#pragma unroll 8
  for (int kk = 0; kk < 32; ++kk) {
    const int k = kb + kk;
    float xi[4], xj[4];
#pragma unroll
    for (int i = 0; i < 4; ++i) xi[i] = PI[ur * 4 + i][k];
#pragma unroll
    for (int j = 0; j < 4; ++j) xj[j] = PJ[uc * 4 + j][k];
#pragma unroll
    for (int i = 0; i < 4; ++i)
#pragma unroll
      for (int j = 0; j < 4; ++j) a[i][j] += xi[i] * xj[j];
  }
  if (h) {
    float* rr = &red[h - 1][u][0];
#pragma unroll
    for (int i = 0; i < 4; ++i)
#pragma unroll
      for (int j = 0; j < 4; ++j) rr[i * 4 + j] = a[i][j];
  }
  __syncthreads();
  if (h == 0) {
#pragma unroll
    for (int i = 0; i < 4; ++i)
#pragma unroll
      for (int j = 0; j < 4; ++j) {
        float s = a[i][j];
#pragma unroll
        for (int q = 0; q < 7; ++q) s += red[q][u][i * 4 + j];
        a[i][j] = s;
      }
    const int gr = I * 32 + ur * 4, gc = J * 32 + uc * 4;
    {
      const int kp = gr >> 1;
      *(uint4*)&Am[kp * 256 + gc] =
          make_uint4(pkh(a[0][0], a[1][0]), pkh(a[0][1], a[1][1]),
                     pkh(a[0][2], a[1][2]), pkh(a[0][3], a[1][3]));
      *(uint4*)&Am[(kp + 1) * 256 + gc] =
          make_uint4(pkh(a[2][0], a[3][0]), pkh(a[2][1], a[3][1]),
                     pkh(a[2][2], a[3][2]), pkh(a[2][3], a[3][3]));
    }
    if (I != J) {
      const int kp = gc >> 1;
      *(uint4*)&Am[kp * 256 + gr] =
          make_uint4(pkh(a[0][0], a[0][1]), pkh(a[1][0], a[1][1]),
                     pkh(a[2][0], a[2][1]), pkh(a[3][0], a[3][1]));
      *(uint4*)&Am[(kp + 1) * 256 + gr] =
          make_uint4(pkh(a[0][2], a[0][3]), pkh(a[1][2], a[1][3]),
                     pkh(a[2][2], a[2][3]), pkh(a[3][2], a[3][3]));
    } else if (ur == uc) {
      tr8[ur] = a[0][0] + a[1][1] + a[2][2] + a[3][3];
    }
  }
  if (I == J) {
    __syncthreads();
    if (t == 0) {
      float s = 0.f;
#pragma unroll
      for (int q = 0; q < 8; ++q) s += tr8[q];
      part[m * 8 + I] = s;
    }
  }
}

// ---------------- NS phase B (Muon quintic): X' = ca*X + cb*(XA) + cc*(XAA) ----------------
// round-7 structure: scalar coefficients, two fixed passes, no register A-cache.
__global__ __launch_bounds__(512) void k_pB(const float* __restrict__ Xs,
                                            const unsigned int* __restrict__ Acp,
                                            const float* __restrict__ part,
                                            float* __restrict__ Xn,
                                            const float qa, const float qb, const float qc,
                                            const int first) {
  const int m = blockIdx.x >> 6, g = blockIdx.x & 63, i0 = g * 4;
  const float* Xm = Xs + (size_t)m * MSZ;
  const uint4* A4 = (const uint4*)(Acp + (size_t)m * (128 * 256));
  float* Xo = Xn + (size_t)m * MSZ;
  const int t = threadIdx.x, h = t >> 6, u = t & 63;
  __shared__ float xs[4][260];
  __shared__ unsigned int xsp[4][132];
  __shared__ unsigned int ysp[4][132];
  __shared__ float red[7][64][17];

  float ca = qa, cb = qb, cc = qc;
  if (first) {
    float tr = 0.f;
#pragma unroll
    for (int q = 0; q < 8; ++q) tr += part[m * 8 + q];
    const float s = 0.15f * sqrtf(tr);     // 1.2 * 2*||C||_F/sqrt(256)
    const float is = 1.f / s, is2 = is * is;
    ca = qa * is;
    cb = qb * is * is2;
    cc = qc * is * is2 * is2;
  }

  if (t < 256) {  // stage X strip: fp32 + f16 pairs along k
    const int r = t >> 6, c16 = t & 63;
    const float4 v = *(const float4*)&Xm[(i0 + r) * 256 + c16 * 4];
    *(float4*)&xs[r][c16 * 4] = v;
    xsp[r][2 * c16]     = pkh(v.x, v.y);
    xsp[r][2 * c16 + 1] = pkh(v.z, v.w);
  }
  __syncthreads();

  const int kp0 = h * 16;
  float accY[4][4];
#pragma unroll
  for (int i = 0; i < 4; ++i)
#pragma unroll
    for (int j = 0; j < 4; ++j) accY[i][j] = 0.f;
#pragma unroll 8
  for (int kk = 0; kk < 16; ++kk) {
    const int kp = kp0 + kk;
    const uint4 aw = A4[kp * 64 + u];
    const half2_t b0 = uh(aw.x), b1 = uh(aw.y), b2 = uh(aw.z), b3 = uh(aw.w);
#pragma unroll
    for (int r = 0; r < 4; ++r) {
      const half2_t xp = uh(xsp[r][kp]);
      accY[r][0] = FDOT2(xp, b0, accY[r][0]);
      accY[r][1] = FDOT2(xp, b1, accY[r][1]);
      accY[r][2] = FDOT2(xp, b2, accY[r][2]);
      accY[r][3] = FDOT2(xp, b3, accY[r][3]);
    }
  }
  if (h) {
    float* rr = &red[h - 1][u][0];
#pragma unroll
    for (int i = 0; i < 4; ++i)
#pragma unroll
      for (int j = 0; j < 4; ++j) rr[i * 4 + j] = accY[i][j];
  }
  __syncthreads();
  float yv[4][4];
  if (h == 0) {
#pragma unroll
    for (int i = 0; i < 4; ++i)
#pragma unroll
      for (int j = 0; j < 4; ++j) {
        float s = accY[i][j];
#pragma unroll
        for (int q = 0; q < 7; ++q) s += red[q][u][i * 4 + j];
        yv[i][j] = s;
      }
#pragma unroll
    for (int i = 0; i < 4; ++i) {
      ysp[i][2 * u]     = pkh(yv[i][0], yv[i][1]);
      ysp[i][2 * u + 1] = pkh(yv[i][2], yv[i][3]);
    }
  }
  __syncthreads();

  float accZ[4][4];
#pragma unroll
  for (int i = 0; i < 4; ++i)
#pragma unroll
    for (int j = 0; j < 4; ++j) accZ[i][j] = 0.f;
#pragma unroll 8
  for (int kk = 0; kk < 16; ++kk) {
    const int kp = kp0 + kk;
    const uint4 aw = A4[kp * 64 + u];
    const half2_t b0 = uh(aw.x), b1 = uh(aw.y), b2 = uh(aw.z), b3 = uh(aw.w);
#pragma unroll
    for (int r = 0; r < 4; ++r) {
      const half2_t yp = uh(ysp[r][kp]);
      accZ[r][0] = FDOT2(yp, b0, accZ[r][0]);
      accZ[r][1] = FDOT2(yp, b1, accZ[r][1]);
      accZ[r][2] = FDOT2(yp, b2, accZ[r][2]);
      accZ[r][3] = FDOT2(yp, b3, accZ[r][3]);
    }
  }
  if (h) {
    float* rr = &red[h - 1][u][0];
#pragma unroll
    for (int i = 0; i < 4; ++i)
#pragma unroll
      for (int j = 0; j < 4; ++j) rr[i * 4 + j] = accZ[i][j];
  }
  __syncthreads();
  if (h == 0) {
#pragma unroll
    for (int i = 0; i < 4; ++i) {
      float o[4];
#pragma unroll
      for (int j = 0; j < 4; ++j) {
        float z = accZ[i][j];
#pragma unroll
        for (int q = 0; q < 7; ++q) z += red[q][u][i * 4 + j];
        o[j] = ca * xs[i][u * 4 + j] + cb * yv[i][j] + cc * z;
      }
      *(float4*)&Xo[(i0 + i) * 256 + u * 4] = make_float4(o[0], o[1], o[2], o[3]);
    }
  }
}

// ---------------- NS phase B9 (degree-9 convergent): X' = sum_{p=0..4} D9_p * X A^p ----------------
// 4 chained passes; all coefficients compile-time; #pragma unroll'd pass loop (no runtime indexing).
__global__ __launch_bounds__(512) void k_pB9(const float* __restrict__ Xs,
                                             const unsigned int* __restrict__ Acp,
                                             float* __restrict__ Xn) {
  const int m = blockIdx.x >> 6, g = blockIdx.x & 63, i0 = g * 4;
  const float* Xm = Xs + (size_t)m * MSZ;
  const uint4* A4 = (const uint4*)(Acp + (size_t)m * (128 * 256));
  float* Xo = Xn + (size_t)m * MSZ;
  const int t = threadIdx.x, h = t >> 6, u = t & 63;
  __shared__ float xs[4][260];
  __shared__ unsigned int buf0[4][132];
  __shared__ unsigned int buf1[4][132];
  __shared__ float red[7][64][17];

  if (t < 256) {
    const int r = t >> 6, c16 = t & 63;
    const float4 v = *(const float4*)&Xm[(i0 + r) * 256 + c16 * 4];
    *(float4*)&xs[r][c16 * 4] = v;
    buf0[r][2 * c16]     = pkh(v.x, v.y);
    buf0[r][2 * c16 + 1] = pkh(v.z, v.w);
  }
  __syncthreads();

  const int kp0 = h * 16;
  float out[4][4];
  if (h == 0) {
#pragma unroll
    for (int i = 0; i < 4; ++i)
#pragma unroll
      for (int j = 0; j < 4; ++j) out[i][j] = D9_0 * xs[i][u * 4 + j];
  }

#pragma unroll
  for (int p = 0; p < 4; ++p) {
    const float cp = (p == 0) ? D9_1 : (p == 1) ? D9_2 : (p == 2) ? D9_3 : D9_4;
    unsigned int (*src)[132] = (p & 1) ? buf1 : buf0;
    unsigned int (*dst)[132] = (p & 1) ? buf0 : buf1;

    float acc[4][4];
#pragma unroll
    for (int i = 0; i < 4; ++i)
#pragma unroll
      for (int j = 0; j < 4; ++j) acc[i][j] = 0.f;
#pragma unroll 8
    for (int kk = 0; kk < 16; ++kk) {
      const int kp = kp0 + kk;
      const uint4 aw = A4[kp * 64 + u];
      const half2_t b0 = uh(aw.x), b1 = uh(aw.y), b2 = uh(aw.z), b3 = uh(aw.w);
#pragma unroll
      for (int r = 0; r < 4; ++r) {
        const half2_t xp = uh(src[r][kp]);
        acc[r][0] = FDOT2(xp, b0, acc[r][0]);
        acc[r][1] = FDOT2(xp, b1, acc[r][1]);
        acc[r][2] = FDOT2(xp, b2, acc[r][2]);
        acc[r][3] = FDOT2(xp, b3, acc[r][3]);
      }
    }
    if (h) {
      float* rr = &red[h - 1][u][0];
#pragma unroll
      for (int i = 0; i < 4; ++i)
#pragma unroll
        for (int j = 0; j < 4; ++j) rr[i * 4 + j] = acc[i][j];
    }
    __syncthreads();
    if (h == 0) {
#pragma unroll
      for (int i = 0; i < 4; ++i) {
        float tv[4];
#pragma unroll
        for (int j = 0; j < 4; ++j) {
          float s = acc[i][j];
#pragma unroll
          for (int q = 0; q < 7; ++q) s += red[q][u][i * 4 + j];
          tv[j] = s;
          out[i][j] += cp * s;
        }
        if (p < 3) {
          dst[i][2 * u]     = pkh(tv[0], tv[1]);
          dst[i][2 * u + 1] = pkh(tv[2], tv[3]);
        }
      }
    }
    __syncthreads();
  }

  if (h == 0) {
#pragma unroll
    for (int i = 0; i < 4; ++i)
      *(float4*)&Xo[(i0 + i) * 256 + u * 4] =
          make_float4(out[i][0], out[i][1], out[i][2], out[i][3]);
  }
}

// ---------------- K4: output assembly ----------------
__global__ __launch_bounds__(256) void k_out(const float* __restrict__ sp,
                                             const float* __restrict__ P,
                                             const int* __restrict__ sel,
                                             float* __restrict__ out) {
  const int t = threadIdx.x;
  if (blockIdx.x < 128) {
    const int b = blockIdx.x;
    __shared__ float hd[256];
    hd[t] = sp[(size_t)b * Kd + t];
    __syncthreads();
    const int s = sel[b];
    if (s < 0) {
      out[(size_t)b * Kd + t] = hd[t];
    } else {
      const float4* prow = (const float4*)(P + (size_t)s * MSZ + t * 256);
      float acc = 0.f;
#pragma unroll 8
      for (int j4 = 0; j4 < 64; ++j4) {
        const float4 p = prow[j4];
        acc += p.x * hd[4 * j4 + 0] + p.y * hd[4 * j4 + 1] +
               p.z * hd[4 * j4 + 2] + p.w * hd[4 * j4 + 3];
      }
      out[(size_t)b * Kd + t] = hd[t] + 0.1f * acc;
    }
  } else {
    const int ci = blockIdx.x - 128;
    const float4* in4 = (const float4*)sp;
    float4* out4 = (float4*)out;
    const int total = Bn * (Kd / 4);
    for (int i = ci * 256 + t; i < total; i += 2048 * 256) {
      const int pos = i & ((Kd / 4) - 1);
      if (pos >= Qd / 4) out4[i] = in4[i];
    }
  }
}

// ---------------- host ----------------
extern "C" void kernel_launch(void* const* d_in, const int* in_sizes, int n_in,
                              void* d_out, int out_size, void* d_ws, size_t ws_size,
                              hipStream_t stream) {
  (void)in_sizes; (void)n_in; (void)out_size; (void)ws_size;
  const float* sp = (const float*)d_in[0];
  const float* W1 = (const float*)d_in[1];
  const float* b1 = (const float*)d_in[2];
  const float* W2 = (const float*)d_in[3];
  const float* b2 = (const float*)d_in[4];
  const float* W3 = (const float*)d_in[5];
  const float* b3 = (const float*)d_in[6];
  const float* ops = (const float*)d_in[7];
  float* out = (float*)d_out;
  float* ws = (float*)d_ws;

  float* h1p  = ws + OFF_H1P;
  float* h1   = ws + OFF_H1;
  int*   sel  = (int*)(ws + OFF_SEL);
  float* part = ws + OFF_PART;
  float* Xa   = ws + OFF_XA;
  float* Xb   = ws + OFF_XB;
  unsigned int* Acp = (unsigned int*)(ws + OFF_ACP);

  k_gemm1<<<NCH, 512, 0, stream>>>(sp, W1, h1p);
  k_red<<<256, 256, 0, stream>>>(h1p, b1, h1);
  k_mlp<<<8, 256, 0, stream>>>(h1, W2, b2, W3, b3, sel);

  // iteration 0 on raw C (scale folded via trace partials)
  k_pA<<<NM * 36, 512, 0, stream>>>(ops, Acp, part);
  k_pB<<<192, 512, 0, stream>>>(ops, Acp, part, Xa, MA, MB, MC, 1);

  float* X = Xa;
  float* Xn = Xb;
  for (int it = 1; it < 8; ++it) {  // its 1..7 Muon
    k_pA<<<NM * 36, 512, 0, stream>>>(X, Acp, part);
    k_pB<<<192, 512, 0, stream>>>(X, Acp, part, Xn, MA, MB, MC, 0);
    float* tmp = X; X = Xn; Xn = tmp;
  }
  // final: degree-9 convergent
  k_pA<<<NM * 36, 512, 0, stream>>>(X, Acp, part);
  k_pB9<<<192, 512, 0, stream>>>(X, Acp, Xn);
  X = Xn;

  k_out<<<128 + 2048, 256, 0, stream>>>(sp, X, sel, out);
}

// Round 10
// 188.340 us; speedup vs baseline: 1.6756x; 1.1637x over previous
//
#include <hip/hip_runtime.h>
#include <math.h>

// ---------------- problem constants ----------------
constexpr int Bn  = 128;
constexpr int Kd  = 65536;    // magnitude dim (phase half of feats is zeros)
constexpr int F1  = 128;
constexpr int F2  = 64;
constexpr int NM  = 3;
constexpr int Qd  = 256;
constexpr int NCH = 512;      // split-K chunks for big GEMM
constexpr int KC  = 128;      // k per chunk
constexpr int MSZ = 256 * 256;

// Muon (growth) quintic Newton-Schulz coefficients
#define MA 3.4445f
#define MB (-4.7750f)
#define MC 2.0315f
// degree-9 convergent NS: x*(315 - 420y + 378y^2 - 180y^3 + 35y^4)/128, y=x^2
#define D9_0 (315.f / 128.f)
#define D9_1 (-420.f / 128.f)
#define D9_2 (378.f / 128.f)
#define D9_3 (-180.f / 128.f)
#define D9_4 (35.f / 128.f)

// ---------------- ws layout (float offsets) ----------------
constexpr size_t OFF_H1P  = 0;                                   // 512*128*128 floats
constexpr size_t OFF_H1   = OFF_H1P + (size_t)NCH * Bn * F1;
constexpr size_t OFF_SEL  = OFF_H1 + (size_t)Bn * F1;
constexpr size_t OFF_PART = OFF_SEL + 128;
constexpr size_t OFF_XA   = OFF_PART + 64;
constexpr size_t OFF_XB   = OFF_XA + (size_t)NM * MSZ;
constexpr size_t OFF_ACP  = OFF_XB + (size_t)NM * MSZ;           // u32: NM*128*256

// ---------------- f16 helpers (NS chain) ----------------
typedef __fp16 half2_t __attribute__((ext_vector_type(2)));
union HU { half2_t h; unsigned int u; };
__device__ __forceinline__ unsigned int pkh(float x, float y) {
  HU v; v.h = __builtin_amdgcn_cvt_pkrtz(x, y); return v.u;
}
__device__ __forceinline__ half2_t uh(unsigned int u) { HU v; v.u = u; return v.h; }

#if __has_builtin(__builtin_amdgcn_fdot2)
#define FDOT2(a, b, c) __builtin_amdgcn_fdot2((a), (b), (c), false)
#else
#define FDOT2(a, b, c) ((c) + (float)(a)[0] * (float)(b)[0] + (float)(a)[1] * (float)(b)[1])
#endif

// ---------------- bf16 helpers (MFMA GEMM) ----------------
typedef short bf16x8 __attribute__((ext_vector_type(8)));
typedef float f32x4 __attribute__((ext_vector_type(4)));
__device__ __forceinline__ unsigned short bh(float x) {   // RNE fp32 -> bf16
  unsigned int bx = __float_as_uint(x);
  return (unsigned short)((bx + 0x7FFFu + ((bx >> 16) & 1u)) >> 16);
}
__device__ __forceinline__ float bf(unsigned short h) {
  return __uint_as_float((unsigned int)h << 16);
}

// ---------------- K1: split-K magnitude GEMM via bf16-split MFMA ----------------
// 512 blocks x 256 thr (4 waves); block = k-chunk of 128, two k64 sub-chunks.
// C = |sp| . W1[:, :65536]^T  ==  hi*hi + hi*lo + lo*hi  (3 MFMA accums, fp32 acc).
// Operands staged [idx][k] k-contiguous bf16; frag = b128 at [l&15][8*(l>>4)].
__global__ __launch_bounds__(256) void k_gemm1(const float* __restrict__ sp,
                                               const float* __restrict__ W1,
                                               float* __restrict__ h1p) {
  __shared__ short Ah[128][72];
  __shared__ short Al[128][72];
  __shared__ short Bh[128][72];
  __shared__ short Bl[128][72];
  const int t = threadIdx.x;
  const int w = t >> 6, l = t & 63;
  const int l15 = l & 15, lg = l >> 4;
  const int ch = blockIdx.x;
  const size_t k0 = (size_t)ch * KC;
  const int srow = t >> 4;          // staging row 0..15 (+16*rep)
  const int skq  = (t & 15) * 4;    // staging k-quad

  f32x4 acc[2][8];
#pragma unroll
  for (int r = 0; r < 2; ++r)
#pragma unroll
    for (int c = 0; c < 8; ++c) acc[r][c] = (f32x4){0.f, 0.f, 0.f, 0.f};

#pragma unroll
  for (int sub = 0; sub < 2; ++sub) {
    __syncthreads();
    const size_t kb = k0 + sub * 64 + skq;
#pragma unroll
    for (int rep = 0; rep < 8; ++rep) {
      const int row = srow + rep * 16;
      const float4 av = *(const float4*)(sp + (size_t)row * Kd + kb);
      const float4 bv = *(const float4*)(W1 + (size_t)row * (2 * Kd) + kb);
      float va[4] = {fabsf(av.x), fabsf(av.y), fabsf(av.z), fabsf(av.w)};
      float vb[4] = {bv.x, bv.y, bv.z, bv.w};
      unsigned short ha[4], la[4], hb[4], lb[4];
#pragma unroll
      for (int e = 0; e < 4; ++e) {
        ha[e] = bh(va[e]); la[e] = bh(va[e] - bf(ha[e]));
        hb[e] = bh(vb[e]); lb[e] = bh(vb[e] - bf(hb[e]));
      }
      *(uint2*)&Ah[row][skq] = make_uint2((unsigned)ha[0] | ((unsigned)ha[1] << 16),
                                          (unsigned)ha[2] | ((unsigned)ha[3] << 16));
      *(uint2*)&Al[row][skq] = make_uint2((unsigned)la[0] | ((unsigned)la[1] << 16),
                                          (unsigned)la[2] | ((unsigned)la[3] << 16));
      *(uint2*)&Bh[row][skq] = make_uint2((unsigned)hb[0] | ((unsigned)hb[1] << 16),
                                          (unsigned)hb[2] | ((unsigned)hb[3] << 16));
      *(uint2*)&Bl[row][skq] = make_uint2((unsigned)lb[0] | ((unsigned)lb[1] << 16),
                                          (unsigned)lb[2] | ((unsigned)lb[3] << 16));
    }
    __syncthreads();
#pragma unroll
    for (int ks = 0; ks < 2; ++ks) {
      const int ko = ks * 32 + lg * 8;
      bf16x8 afh[2], afl[2];
#pragma unroll
      for (int r = 0; r < 2; ++r) {
        const int row = w * 32 + r * 16 + l15;
        afh[r] = *(const bf16x8*)&Ah[row][ko];
        afl[r] = *(const bf16x8*)&Al[row][ko];
      }
#pragma unroll
      for (int c = 0; c < 8; ++c) {
        const int col = c * 16 + l15;
        const bf16x8 bfh = *(const bf16x8*)&Bh[col][ko];
        const bf16x8 bfl = *(const bf16x8*)&Bl[col][ko];
#pragma unroll
        for (int r = 0; r < 2; ++r) {
          acc[r][c] = __builtin_amdgcn_mfma_f32_16x16x32_bf16(afh[r], bfh, acc[r][c], 0, 0, 0);
          acc[r][c] = __builtin_amdgcn_mfma_f32_16x16x32_bf16(afh[r], bfl, acc[r][c], 0, 0, 0);
          acc[r][c] = __builtin_amdgcn_mfma_f32_16x16x32_bf16(afl[r], bfh, acc[r][c], 0, 0, 0);
        }
      }
    }
  }

  // D layout per tile: row = (l>>4)*4 + reg, col = l&15
  float* outp = h1p + (size_t)ch * (Bn * F1);
#pragma unroll
  for (int r = 0; r < 2; ++r)
#pragma unroll
    for (int c = 0; c < 8; ++c) {
      const int col = c * 16 + l15;
#pragma unroll
      for (int reg = 0; reg < 4; ++reg) {
        const int row = w * 32 + r * 16 + lg * 4 + reg;
        outp[row * F1 + col] = acc[r][c][reg];
      }
    }
}

// ---------------- K1b: reduce partials + bias + relu (512 chunks) ----------------
__global__ __launch_bounds__(256) void k_red(const float* __restrict__ h1p,
                                             const float* __restrict__ b1,
                                             float* __restrict__ h1) {
  const int t = threadIdx.x;
  const int ol = t & 63;
  const int g = t >> 6;
  const int o = blockIdx.x * 64 + ol;
  double s = 0.0;
#pragma unroll 8
  for (int c = g * 128; c < g * 128 + 128; ++c)
    s += (double)h1p[(size_t)c * (Bn * F1) + o];
  __shared__ double red[4][64];
  red[g][ol] = s;
  __syncthreads();
  if (g == 0) {
    const double v = red[0][ol] + red[1][ol] + red[2][ol] + red[3][ol];
    const float r = (float)v + b1[o & 127];
    h1[o] = fmaxf(r, 0.f);
  }
}

// ---------------- K2: small MLP + syndrome + selection ----------------
__global__ __launch_bounds__(256) void k_mlp(const float* __restrict__ h1,
                                             const float* __restrict__ W2,
                                             const float* __restrict__ b2,
                                             const float* __restrict__ W3,
                                             const float* __restrict__ b3,
                                             int* __restrict__ sel) {
  const int t = threadIdx.x;
  const int b0 = blockIdx.x * 16;
  __shared__ float h2s[16 * 64];
  for (int o = t; o < 16 * 64; o += 256) {
    const int bl = o >> 6, j = o & 63;
    const float* hr = h1 + (b0 + bl) * F1;
    const float* wr = W2 + j * F1;
    float s = b2[j];
    for (int k = 0; k < F1; ++k) s += hr[k] * wr[k];
    h2s[o] = fmaxf(s, 0.f);
  }
  __syncthreads();
  if (t < 16) {
    const int b = b0 + t;
    float best = -1.f;
    int bi = 0;
    bool needed = false;
    for (int j = 0; j < 8; ++j) {
      double s = (double)b3[j];
      const float* wr = W3 + j * F2;
      for (int k = 0; k < F2; ++k) s += (double)h2s[t * F2 + k] * (double)wr[k];
      const float a = fabsf((float)s);
      if (a > 1e-4f) needed = true;
      if (a > best) { best = a; bi = j; }
    }
    sel[b] = needed ? (bi % NM) : -1;
  }
}

// ---------------- NS phase A: A = X^T X -> f16 colpk (symmetric 32x32 tiles) ----------------
__global__ __launch_bounds__(512) void k_pA(const float* __restrict__ Xs,
                                            unsigned int* __restrict__ Acp,
                                            float* __restrict__ part) {
  const int bid = blockIdx.x;
  const int m = bid / 36;
  int rem = bid % 36;
  int I = 0;
  while (rem >= 8 - I) { rem -= 8 - I; ++I; }
  const int J = I + rem;
  const float* Xm = Xs + (size_t)m * MSZ;
  unsigned int* Am = Acp + (size_t)m * (128 * 256);
  __shared__ float PI[32][260];
  __shared__ float PJb[32][260];
  __shared__ float red[7][64][17];
  __shared__ float tr8[8];
  float (*PJ)[260] = (I == J) ? PI : PJb;
  const int t = threadIdx.x;

#pragma unroll
  for (int it = 0; it < 4; ++it) {
    const int task = it * 512 + t;
    const int k = task >> 3, c4 = task & 7;
    const float4 vI = *(const float4*)&Xm[k * 256 + I * 32 + c4 * 4];
#pragma unroll
    for (int e = 0; e < 4; ++e) PI[c4 * 4 + e][k] = (&vI.x)[e];
    if (I != J) {
      const float4 vJ = *(const float4*)&Xm[k * 256 + J * 32 + c4 * 4];
#pragma unroll
      for (int e = 0; e < 4; ++e) PJb[c4 * 4 + e][k] = (&vJ.x)[e];
    }
  }
  __syncthreads();

  const int h = t >> 6, u = t & 63, ur = u >> 3, uc = u & 7;
  float a[4][4];
#pragma unroll
  for (int i = 0; i < 4; ++i)
#pragma unroll
    for (int j = 0; j < 4; ++j) a[i][j] = 0.f;

  const int kb = h * 32;
#pragma unroll 8
  for (int kk = 0; kk < 32; ++kk) {
    const int k = kb + kk;
    float xi[4], xj[4];
#pragma unroll
    for (int i = 0; i < 4; ++i) xi[i] = PI[ur * 4 + i][k];
#pragma unroll
    for (int j = 0; j < 4; ++j) xj[j] = PJ[uc * 4 + j][k];
#pragma unroll
    for (int i = 0; i < 4; ++i)
#pragma unroll
      for (int j = 0; j < 4; ++j) a[i][j] += xi[i] * xj[j];
  }
  if (h) {
    float* rr = &red[h - 1][u][0];
#pragma unroll
    for (int i = 0; i < 4; ++i)
#pragma unroll
      for (int j = 0; j < 4; ++j) rr[i * 4 + j] = a[i][j];
  }
  __syncthreads();
  if (h == 0) {
#pragma unroll
    for (int i = 0; i < 4; ++i)
#pragma unroll
      for (int j = 0; j < 4; ++j) {
        float s = a[i][j];
#pragma unroll
        for (int q = 0; q < 7; ++q) s += red[q][u][i * 4 + j];
        a[i][j] = s;
      }
    const int gr = I * 32 + ur * 4, gc = J * 32 + uc * 4;
    {
      const int kp = gr >> 1;
      *(uint4*)&Am[kp * 256 + gc] =
          make_uint4(pkh(a[0][0], a[1][0]), pkh(a[0][1], a[1][1]),
                     pkh(a[0][2], a[1][2]), pkh(a[0][3], a[1][3]));
      *(uint4*)&Am[(kp + 1) * 256 + gc] =
          make_uint4(pkh(a[2][0], a[3][0]), pkh(a[2][1], a[3][1]),
                     pkh(a[2][2], a[3][2]), pkh(a[2][3], a[3][3]));
    }
    if (I != J) {
      const int kp = gc >> 1;
      *(uint4*)&Am[kp * 256 + gr] =
          make_uint4(pkh(a[0][0], a[0][1]), pkh(a[1][0], a[1][1]),
                     pkh(a[2][0], a[2][1]), pkh(a[3][0], a[3][1]));
      *(uint4*)&Am[(kp + 1) * 256 + gr] =
          make_uint4(pkh(a[0][2], a[0][3]), pkh(a[1][2], a[1][3]),
                     pkh(a[2][2], a[2][3]), pkh(a[3][2], a[3][3]));
    } else if (ur == uc) {
      tr8[ur] = a[0][0] + a[1][1] + a[2][2] + a[3][3];
    }
  }
  if (I == J) {
    __syncthreads();
    if (t == 0) {
      float s = 0.f;
#pragma unroll
      for (int q = 0; q < 8; ++q) s += tr8[q];
      part[m * 8 + I] = s;
    }
  }
}

// ---------------- NS phase B (Muon quintic): X' = ca*X + cb*(XA) + cc*(XAA) ----------------
__global__ __launch_bounds__(512) void k_pB(const float* __restrict__ Xs,
                                            const unsigned int* __restrict__ Acp,
                                            const float* __restrict__ part,
                                            float* __restrict__ Xn,
                                            const float qa, const float qb, const float qc,
                                            const int first) {
  const int m = blockIdx.x >> 6, g = blockIdx.x & 63, i0 = g * 4;
  const float* Xm = Xs + (size_t)m * MSZ;
  const uint4* A4 = (const uint4*)(Acp + (size_t)m * (128 * 256));
  float* Xo = Xn + (size_t)m * MSZ;
  const int t = threadIdx.x, h = t >> 6, u = t & 63;
  __shared__ float xs[4][260];
  __shared__ unsigned int xsp[4][132];
  __shared__ unsigned int ysp[4][132];
  __shared__ float red[7][64][17];

  float ca = qa, cb = qb, cc = qc;
  if (first) {
    float tr = 0.f;
#pragma unroll
    for (int q = 0; q < 8; ++q) tr += part[m * 8 + q];
    const float s = 0.15f * sqrtf(tr);     // 1.2 * 2*||C||_F/sqrt(256)
    const float is = 1.f / s, is2 = is * is;
    ca = qa * is;
    cb = qb * is * is2;
    cc = qc * is * is2 * is2;
  }

  if (t < 256) {
    const int r = t >> 6, c16 = t & 63;
    const float4 v = *(const float4*)&Xm[(i0 + r) * 256 + c16 * 4];
    *(float4*)&xs[r][c16 * 4] = v;
    xsp[r][2 * c16]     = pkh(v.x, v.y);
    xsp[r][2 * c16 + 1] = pkh(v.z, v.w);
  }
  __syncthreads();

  const int kp0 = h * 16;
  float accY[4][4];
#pragma unroll
  for (int i = 0; i < 4; ++i)
#pragma unroll
    for (int j = 0; j < 4; ++j) accY[i][j] = 0.f;
#pragma unroll 8
  for (int kk = 0; kk < 16; ++kk) {
    const int kp = kp0 + kk;
    const uint4 aw = A4[kp * 64 + u];
    const half2_t b0 = uh(aw.x), b1 = uh(aw.y), b2 = uh(aw.z), b3 = uh(aw.w);
#pragma unroll
    for (int r = 0; r < 4; ++r) {
      const half2_t xp = uh(xsp[r][kp]);
      accY[r][0] = FDOT2(xp, b0, accY[r][0]);
      accY[r][1] = FDOT2(xp, b1, accY[r][1]);
      accY[r][2] = FDOT2(xp, b2, accY[r][2]);
      accY[r][3] = FDOT2(xp, b3, accY[r][3]);
    }
  }
  if (h) {
    float* rr = &red[h - 1][u][0];
#pragma unroll
    for (int i = 0; i < 4; ++i)
#pragma unroll
      for (int j = 0; j < 4; ++j) rr[i * 4 + j] = accY[i][j];
  }
  __syncthreads();
  float yv[4][4];
  if (h == 0) {
#pragma unroll
    for (int i = 0; i < 4; ++i)
#pragma unroll
      for (int j = 0; j < 4; ++j) {
        float s = accY[i][j];
#pragma unroll
        for (int q = 0; q < 7; ++q) s += red[q][u][i * 4 + j];
        yv[i][j] = s;
      }
#pragma unroll
    for (int i = 0; i < 4; ++i) {
      ysp[i][2 * u]     = pkh(yv[i][0], yv[i][1]);
      ysp[i][2 * u + 1] = pkh(yv[i][2], yv[i][3]);
    }
  }
  __syncthreads();

  float accZ[4][4];
#pragma unroll
  for (int i = 0; i < 4; ++i)
#pragma unroll
    for (int j = 0; j < 4; ++j) accZ[i][j] = 0.f;
#pragma unroll 8
  for (int kk = 0; kk < 16; ++kk) {
    const int kp = kp0 + kk;
    const uint4 aw = A4[kp * 64 + u];
    const half2_t b0 = uh(aw.x), b1 = uh(aw.y), b2 = uh(aw.z), b3 = uh(aw.w);
#pragma unroll
    for (int r = 0; r < 4; ++r) {
      const half2_t yp = uh(ysp[r][kp]);
      accZ[r][0] = FDOT2(yp, b0, accZ[r][0]);
      accZ[r][1] = FDOT2(yp, b1, accZ[r][1]);
      accZ[r][2] = FDOT2(yp, b2, accZ[r][2]);
      accZ[r][3] = FDOT2(yp, b3, accZ[r][3]);
    }
  }
  if (h) {
    float* rr = &red[h - 1][u][0];
#pragma unroll
    for (int i = 0; i < 4; ++i)
#pragma unroll
      for (int j = 0; j < 4; ++j) rr[i * 4 + j] = accZ[i][j];
  }
  __syncthreads();
  if (h == 0) {
#pragma unroll
    for (int i = 0; i < 4; ++i) {
      float o[4];
#pragma unroll
      for (int j = 0; j < 4; ++j) {
        float z = accZ[i][j];
#pragma unroll
        for (int q = 0; q < 7; ++q) z += red[q][u][i * 4 + j];
        o[j] = ca * xs[i][u * 4 + j] + cb * yv[i][j] + cc * z;
      }
      *(float4*)&Xo[(i0 + i) * 256 + u * 4] = make_float4(o[0], o[1], o[2], o[3]);
    }
  }
}

// ---------------- NS phase B9 (degree-9 convergent): X' = sum_{p=0..4} D9_p * X A^p ----------------
__global__ __launch_bounds__(512) void k_pB9(const float* __restrict__ Xs,
                                             const unsigned int* __restrict__ Acp,
                                             float* __restrict__ Xn) {
  const int m = blockIdx.x >> 6, g = blockIdx.x & 63, i0 = g * 4;
  const float* Xm = Xs + (size_t)m * MSZ;
  const uint4* A4 = (const uint4*)(Acp + (size_t)m * (128 * 256));
  float* Xo = Xn + (size_t)m * MSZ;
  const int t = threadIdx.x, h = t >> 6, u = t & 63;
  __shared__ float xs[4][260];
  __shared__ unsigned int buf0[4][132];
  __shared__ unsigned int buf1[4][132];
  __shared__ float red[7][64][17];

  if (t < 256) {
    const int r = t >> 6, c16 = t & 63;
    const float4 v = *(const float4*)&Xm[(i0 + r) * 256 + c16 * 4];
    *(float4*)&xs[r][c16 * 4] = v;
    buf0[r][2 * c16]     = pkh(v.x, v.y);
    buf0[r][2 * c16 + 1] = pkh(v.z, v.w);
  }
  __syncthreads();

  const int kp0 = h * 16;
  float out[4][4];
  if (h == 0) {
#pragma unroll
    for (int i = 0; i < 4; ++i)
#pragma unroll
      for (int j = 0; j < 4; ++j) out[i][j] = D9_0 * xs[i][u * 4 + j];
  }

#pragma unroll
  for (int p = 0; p < 4; ++p) {
    const float cp = (p == 0) ? D9_1 : (p == 1) ? D9_2 : (p == 2) ? D9_3 : D9_4;
    unsigned int (*src)[132] = (p & 1) ? buf1 : buf0;
    unsigned int (*dst)[132] = (p & 1) ? buf0 : buf1;

    float acc[4][4];
#pragma unroll
    for (int i = 0; i < 4; ++i)
#pragma unroll
      for (int j = 0; j < 4; ++j) acc[i][j] = 0.f;
#pragma unroll 8
    for (int kk = 0; kk < 16; ++kk) {
      const int kp = kp0 + kk;
      const uint4 aw = A4[kp * 64 + u];
      const half2_t b0 = uh(aw.x), b1 = uh(aw.y), b2 = uh(aw.z), b3 = uh(aw.w);
#pragma unroll
      for (int r = 0; r < 4; ++r) {
        const half2_t xp = uh(src[r][kp]);
        acc[r][0] = FDOT2(xp, b0, acc[r][0]);
        acc[r][1] = FDOT2(xp, b1, acc[r][1]);
        acc[r][2] = FDOT2(xp, b2, acc[r][2]);
        acc[r][3] = FDOT2(xp, b3, acc[r][3]);
      }
    }
    if (h) {
      float* rr = &red[h - 1][u][0];
#pragma unroll
      for (int i = 0; i < 4; ++i)
#pragma unroll
        for (int j = 0; j < 4; ++j) rr[i * 4 + j] = acc[i][j];
    }
    __syncthreads();
    if (h == 0) {
#pragma unroll
      for (int i = 0; i < 4; ++i) {
        float tv[4];
#pragma unroll
        for (int j = 0; j < 4; ++j) {
          float s = acc[i][j];
#pragma unroll
          for (int q = 0; q < 7; ++q) s += red[q][u][i * 4 + j];
          tv[j] = s;
          out[i][j] += cp * s;
        }
        if (p < 3) {
          dst[i][2 * u]     = pkh(tv[0], tv[1]);
          dst[i][2 * u + 1] = pkh(tv[2], tv[3]);
        }
      }
    }
    __syncthreads();
  }

  if (h == 0) {
#pragma unroll
    for (int i = 0; i < 4; ++i)
      *(float4*)&Xo[(i0 + i) * 256 + u * 4] =
          make_float4(out[i][0], out[i][1], out[i][2], out[i][3]);
  }
}

// ---------------- K4: output assembly ----------------
__global__ __launch_bounds__(256) void k_out(const float* __restrict__ sp,
                                             const float* __restrict__ P,
                                             const int* __restrict__ sel,
                                             float* __restrict__ out) {
  const int t = threadIdx.x;
  if (blockIdx.x < 128) {
    const int b = blockIdx.x;
    __shared__ float hd[256];
    hd[t] = sp[(size_t)b * Kd + t];
    __syncthreads();
    const int s = sel[b];
    if (s < 0) {
      out[(size_t)b * Kd + t] = hd[t];
    } else {
      const float4* prow = (const float4*)(P + (size_t)s * MSZ + t * 256);
      float acc = 0.f;
#pragma unroll 8
      for (int j4 = 0; j4 < 64; ++j4) {
        const float4 p = prow[j4];
        acc += p.x * hd[4 * j4 + 0] + p.y * hd[4 * j4 + 1] +
               p.z * hd[4 * j4 + 2] + p.w * hd[4 * j4 + 3];
      }
      out[(size_t)b * Kd + t] = hd[t] + 0.1f * acc;
    }
  } else {
    const int ci = blockIdx.x - 128;
    const float4* in4 = (const float4*)sp;
    float4* out4 = (float4*)out;
    const int total = Bn * (Kd / 4);
    for (int i = ci * 256 + t; i < total; i += 2048 * 256) {
      const int pos = i & ((Kd / 4) - 1);
      if (pos >= Qd / 4) out4[i] = in4[i];
    }
  }
}

// ---------------- host ----------------
extern "C" void kernel_launch(void* const* d_in, const int* in_sizes, int n_in,
                              void* d_out, int out_size, void* d_ws, size_t ws_size,
                              hipStream_t stream) {
  (void)in_sizes; (void)n_in; (void)out_size; (void)ws_size;
  const float* sp = (const float*)d_in[0];
  const float* W1 = (const float*)d_in[1];
  const float* b1 = (const float*)d_in[2];
  const float* W2 = (const float*)d_in[3];
  const float* b2 = (const float*)d_in[4];
  const float* W3 = (const float*)d_in[5];
  const float* b3 = (const float*)d_in[6];
  const float* ops = (const float*)d_in[7];
  float* out = (float*)d_out;
  float* ws = (float*)d_ws;

  float* h1p  = ws + OFF_H1P;
  float* h1   = ws + OFF_H1;
  int*   sel  = (int*)(ws + OFF_SEL);
  float* part = ws + OFF_PART;
  float* Xa   = ws + OFF_XA;
  float* Xb   = ws + OFF_XB;
  unsigned int* Acp = (unsigned int*)(ws + OFF_ACP);

  k_gemm1<<<NCH, 256, 0, stream>>>(sp, W1, h1p);
  k_red<<<256, 256, 0, stream>>>(h1p, b1, h1);
  k_mlp<<<8, 256, 0, stream>>>(h1, W2, b2, W3, b3, sel);

  // iteration 0 on raw C (scale folded via trace partials)
  k_pA<<<NM * 36, 512, 0, stream>>>(ops, Acp, part);
  k_pB<<<192, 512, 0, stream>>>(ops, Acp, part, Xa, MA, MB, MC, 1);

  float* X = Xa;
  float* Xn = Xb;
  for (int it = 1; it < 7; ++it) {  // its 1..6 Muon (7 Muon total)
    k_pA<<<NM * 36, 512, 0, stream>>>(X, Acp, part);
    k_pB<<<192, 512, 0, stream>>>(X, Acp, part, Xn, MA, MB, MC, 0);
    float* tmp = X; X = Xn; Xn = tmp;
  }
  // final: degree-9 convergent
  k_pA<<<NM * 36, 512, 0, stream>>>(X, Acp, part);
  k_pB9<<<192, 512, 0, stream>>>(X, Acp, Xn);
  X = Xn;

  k_out<<<128 + 2048, 256, 0, stream>>>(sp, X, sel, out);
}